// Round 16
// baseline (1319.464 us; speedup 1.0000x reference)
//
#include <hip/hip_runtime.h>
#include <hip/hip_bf16.h>
#include <cstdint>

#define T_TOK 4096
#define H_DIM 1024
#define F_DIM 2048
#define E_NUM 8
#define MAXT256 39
#define MAXROWS (MAXT256*256)   // 9984 padded entry rows

typedef __attribute__((ext_vector_type(8))) short bf16x8;
typedef __attribute__((ext_vector_type(4))) float f32x4;

__device__ __forceinline__ unsigned short f2bf(float f){
  union { float f; uint32_t u; } c; c.f = f;
  uint32_t u = c.u;
  uint32_t r = (u + 0x7fffu + ((u >> 16) & 1u)) >> 16;
  return (unsigned short)r;
}
__device__ __forceinline__ float bf2f(unsigned short u){
  union { uint32_t u; float f; } c; c.u = ((uint32_t)u) << 16;
  return c.f;
}

// expert lookup from counts via unrolled prefix
#define EXPERT_PREFIX(tile, counts, e, ts_e, n_e, btot) do{ \
  btot = 0; e = 0; ts_e = 0; n_e = 0; \
  _Pragma("unroll") for (int i_=0;i_<E_NUM;i_++){ \
    int cnt_ = (counts)[i_]; \
    if ((tile) >= btot){ e = i_; ts_e = btot; n_e = cnt_; } \
    btot += (cnt_ + 255) >> 8; } }while(0)

// ---- pre-pass: router (blocks 0..127) + w1/w3 fp32->bf16 -------------------
__global__ __launch_bounds__(256) void k_pre(const float* __restrict__ x,
                                             const float* __restrict__ rw,
                                             const float* __restrict__ w1,
                                             const float* __restrict__ w3,
                                             unsigned short* __restrict__ w1b,
                                             unsigned short* __restrict__ w3b,
                                             unsigned short* __restrict__ xb,
                                             int* __restrict__ counts,
                                             int* __restrict__ topi,
                                             float* __restrict__ topv){
  __shared__ float lrw[E_NUM][8][132];
  __shared__ int hist[E_NUM];
  int tid = threadIdx.x;
  if (blockIdx.x < 128){
    if (tid < E_NUM) hist[tid] = 0;
    for (int i = tid; i < E_NUM*H_DIM/4; i += 256){
      int idx = i*4;
      int e = idx >> 10, rem = idx & 1023, c = rem >> 7, j = rem & 127;
      float4 v = reinterpret_cast<const float4*>(rw)[i];
      *reinterpret_cast<float4*>(&lrw[e][c][j]) = v;
    }
    __syncthreads();
    int t = blockIdx.x*32 + (tid >> 3);
    int c = tid & 7;
    const float4* xr = reinterpret_cast<const float4*>(x + (size_t)t*H_DIM + c*128);
    ushort4* xw = reinterpret_cast<ushort4*>(xb + (size_t)t*H_DIM + c*128);
    double acc[E_NUM];
#pragma unroll
    for (int e=0;e<E_NUM;e++) acc[e] = 0.0;
    for (int j4=0; j4<32; ++j4){
      float4 v = xr[j4];
      ushort4 o;
      o.x = f2bf(v.x); o.y = f2bf(v.y); o.z = f2bf(v.z); o.w = f2bf(v.w);
      xw[j4] = o;
#pragma unroll
      for (int e=0;e<E_NUM;e++){
        float4 r = *reinterpret_cast<const float4*>(&lrw[e][c][j4*4]);
        acc[e] += (double)v.x*(double)r.x + (double)v.y*(double)r.y
                + (double)v.z*(double)r.z + (double)v.w*(double)r.w;
      }
    }
#pragma unroll
    for (int e=0;e<E_NUM;e++){
      double s = acc[e];
      s += __shfl_xor(s, 1, 64);
      s += __shfl_xor(s, 2, 64);
      s += __shfl_xor(s, 4, 64);
      acc[e] = s;
    }
    if (c == 0){
      int i0 = 0; double v0 = acc[0];
      for (int e=1;e<E_NUM;e++) if (acc[e] > v0){ v0 = acc[e]; i0 = e; }
      int i1 = -1; double v1 = -1e300;
      for (int e=0;e<E_NUM;e++) if (e != i0 && acc[e] > v1){ v1 = acc[e]; i1 = e; }
      float w0 = 1.0f/(1.0f + expf((float)(v1 - v0)));
      topi[2*t] = i0; topi[2*t+1] = i1;
      topv[2*t] = w0; topv[2*t+1] = 1.0f - w0;
      atomicAdd(&hist[i0], 1); atomicAdd(&hist[i1], 1);
    }
    __syncthreads();
    if (tid < E_NUM && hist[tid]) atomicAdd(&counts[tid], hist[tid]);
  } else {
    int b2 = blockIdx.x - 128;
    int seg = b2 >> 11;
    int b   = b2 & 2047;
    const float* s = seg==0 ? w1 : w3;
    unsigned short* d = seg==0 ? w1b : w3b;
    const int n4 = E_NUM*F_DIM*H_DIM/4;
    for (int i = b*256 + tid; i < n4; i += 2048*256){
      float4 v = reinterpret_cast<const float4*>(s)[i];
      ushort4 o;
      o.x = f2bf(v.x); o.y = f2bf(v.y); o.z = f2bf(v.z); o.w = f2bf(v.w);
      reinterpret_cast<ushort4*>(d)[i] = o;
    }
  }
}

// ---------------- fill grouped entry lists + inverse map --------------------
__global__ __launch_bounds__(256) void k_fill(const int* __restrict__ topi,
                                              const int* __restrict__ counts,
                                              int* __restrict__ cursors,
                                              int* __restrict__ entries,
                                              int* __restrict__ slotof){
  __shared__ int ts[E_NUM];
  if (threadIdx.x == 0){
    int b = 0;
    for (int e=0;e<E_NUM;e++){ ts[e] = b; b += (counts[e] + 255) >> 8; }
  }
  __syncthreads();
  int t = blockIdx.x*256 + threadIdx.x;
  if (t >= T_TOK) return;
#pragma unroll
  for (int k=0;k<2;k++){
    int e = topi[2*t+k];
    int pos = atomicAdd(&cursors[e], 1);
    int slot = ts[e]*256 + pos;
    entries[slot] = 2*t + k;
    slotof[2*t+k] = slot;
  }
}

// ---------------- staging macro ---------------------------------------------
#define GLD(src, dst_us) __builtin_amdgcn_global_load_lds( \
  (const __attribute__((address_space(1))) unsigned int*)(src), \
  (__attribute__((address_space(3))) unsigned int*)(lds + (dst_us)), 16, 0, 0)

// ---------------- 256x256 SINGLE-BUFFER K-loop (2 blocks/CU) ----------------
// LDS = 64 KiB: parts 0=A0,1=A1,2=B0,3=B1 (16 KiB each). Per K-tile:
// syncthreads (readers done) -> stage 8 gload_lds -> syncthreads (implicit
// vmcnt(0)+lgkmcnt(0) drain) -> ds_read frags + 64 MFMA, compiler-scheduled.
// Cross-block overlap (2 blocks/CU) hides the drain (m97/m114 mechanism).

#define STG1(X, s0, s1, kS) do{ \
  GLD((s0) + (kS)*64, (X)*8192 + dstb0); \
  GLD((s1) + (kS)*64, (X)*8192 + dstb1); }while(0)

#define LDA1(QR) do{ const char* p_ = (const char*)lds + (QR)*16384; \
  _Pragma("unroll") for (int m_=0;m_<4;m_++) \
  _Pragma("unroll") for (int ks_=0;ks_<2;ks_++) \
    a[m_][ks_] = *(const bf16x8*)(p_ + aoff[m_][ks_]); }while(0)

#define LDB1(QC, breg) do{ const char* p_ = (const char*)lds + (2+(QC))*16384; \
  _Pragma("unroll") for (int n_=0;n_<2;n_++) \
  _Pragma("unroll") for (int ks_=0;ks_<2;ks_++) \
    breg[n_][ks_] = *(const bf16x8*)(p_ + boff[n_][ks_]); }while(0)

#define MM(QR, QC, breg) do{ \
  _Pragma("unroll") for (int m_=0;m_<4;m_++) \
  _Pragma("unroll") for (int n_=0;n_<2;n_++) \
  _Pragma("unroll") for (int ks_=0;ks_<2;ks_++) \
    acc[QR][QC][m_][n_] = __builtin_amdgcn_mfma_f32_16x16x32_bf16(a[m_][ks_], breg[n_][ks_], acc[QR][QC][m_][n_], 0,0,0); }while(0)

#define KLOOP_SB(NTILES) do{ \
  _Pragma("unroll 1") for (int T=0; T<(NTILES); ++T){ \
    __syncthreads(); \
    STG1(0, sA[0][0], sA[0][1], T); \
    STG1(2, sB[0][0], sB[0][1], T); \
    STG1(3, sB[1][0], sB[1][1], T); \
    STG1(1, sA[1][0], sA[1][1], T); \
    __syncthreads(); \
    LDA1(0); LDB1(0,bA); LDB1(1,bB); \
    MM(0,0,bA); MM(0,1,bB); \
    LDA1(1); \
    MM(1,0,bA); MM(1,1,bB); \
  } \
}while(0)

// ---------------- phase 1: 256x256 grouped GEMM + SiLU ----------------------
// blocks >= 624 convert w2 fp32->bf16 (dispatch last -> fill straggler slots)
__global__ __launch_bounds__(512, 4) void k_ffn1(const unsigned short* __restrict__ xb,
                                                 const unsigned short* __restrict__ w1b,
                                                 const unsigned short* __restrict__ w3b,
                                                 const int* __restrict__ counts,
                                                 const int* __restrict__ entries,
                                                 unsigned short* __restrict__ hidden,
                                                 const float* __restrict__ w2,
                                                 unsigned short* __restrict__ w2b){
  extern __shared__ unsigned short lds[];
  int flat = blockIdx.x;
  if (flat >= 624){
    int b2 = flat - 624;                    // [0,384): w2 convert, 512 threads
    const int n4 = E_NUM*F_DIM*H_DIM/4;
    for (int i = b2*512 + (int)threadIdx.x; i < n4; i += 384*512){
      float4 v = reinterpret_cast<const float4*>(w2)[i];
      ushort4 o;
      o.x = f2bf(v.x); o.y = f2bf(v.y); o.z = f2bf(v.z); o.w = f2bf(v.w);
      reinterpret_cast<ushort4*>(w2b)[i] = o;
    }
    return;
  }
  int nw = (flat & 7)*78 + (flat >> 3);     // 624 = 8*78 bijective XCD chunking
  int tile = nw % MAXT256;
  int nt   = nw / MAXT256;
  int e, ts_e, n_e, btot;
  EXPERT_PREFIX(tile, counts, e, ts_e, n_e, btot);
  if (tile >= btot) return;
  int row0 = (tile - ts_e)*256;
  int ebase = ts_e*256;

  int tid = threadIdx.x, lane = tid & 63, wid = tid >> 6;
  int wm = wid >> 2, wn = wid & 3;          // 2 x 4 wave grid

  const unsigned short* sA[2][2];
  const unsigned short* sB[2][2];
#pragma unroll
  for (int h=0;h<2;h++){
#pragma unroll
    for (int i=0;i<2;i++){
      int idx = i*512 + tid;
      int r = idx >> 3, seg = idx & 7;
      int sc = (seg ^ (r & 7))*8;
      int br = ((r>>6)<<7) | (h<<6) | (r & 63);   // interleaved A halves (bit6)
      int rr = row0 + br; rr = rr < n_e ? rr : (n_e - 1);
      int tokr = entries[ebase + rr] >> 1;
      sA[h][i] = xb + (size_t)tokr*H_DIM + sc;
      const unsigned short* w = h ? w3b : w1b;    // B part2=w1(gate), part3=w3(up)
      sB[h][i] = w + ((size_t)e*F_DIM + nt*128 + r)*H_DIM + sc;
    }
  }
  int dstb0 = wid*512;
  int dstb1 = 4096 + wid*512;

  int aoff[4][2], boff[2][2];
#pragma unroll
  for (int m=0;m<4;m++){
    int ia = wm*64 + m*16 + (lane & 15);
#pragma unroll
    for (int ks=0;ks<2;ks++)
      aoff[m][ks] = ia*128 + ((ks*64 + (lane>>4)*16) ^ ((ia & 7) << 4));
  }
#pragma unroll
  for (int n=0;n<2;n++){
    int ib = wn*32 + n*16 + (lane & 15);
#pragma unroll
    for (int ks=0;ks<2;ks++)
      boff[n][ks] = ib*128 + ((ks*64 + (lane>>4)*16) ^ ((ib & 7) << 4));
  }

  f32x4 acc[2][2][4][2];
#pragma unroll
  for (int qr=0;qr<2;qr++)
#pragma unroll
  for (int qc=0;qc<2;qc++)
#pragma unroll
  for (int m=0;m<4;m++)
#pragma unroll
  for (int n=0;n<2;n++) acc[qr][qc][m][n] = {0.f,0.f,0.f,0.f};

  bf16x8 a[4][2], bA[2][2], bB[2][2];

  KLOOP_SB(16);

  // SiLU epilogue: gate=acc[qr][0], up=acc[qr][1]
  int r16 = ((lane >> 4) & 3)*4;
#pragma unroll
  for (int qr=0;qr<2;qr++){
#pragma unroll
    for (int m=0;m<4;m++){
#pragma unroll
      for (int j=0;j<4;j++){
        int br = wm*128 + qr*64 + m*16 + r16 + j;
        if (row0 + br < n_e){
          size_t rowbase = (size_t)(ebase + row0 + br)*F_DIM + nt*128 + wn*32;
#pragma unroll
          for (int n=0;n<2;n++){
            float g = acc[qr][0][m][n][j];
            float u = acc[qr][1][m][n][j];
            float h = (g / (1.f + __expf(-g))) * u;
            hidden[rowbase + n*16 + (lane & 15)] = f2bf(h);
          }
        }
      }
    }
  }
}

// ---------------- phase 2: 256x256 grouped GEMM, K-split x3, bf16 partials --
// Grid 468 = 39 x (4 nt x 3 kh). K-ranges {12,12,8}. Partials p[kh][slot][H]
// bf16 plain stores (no atomics), aliased onto dead w1b/w3b (61.3 MB).
__global__ __launch_bounds__(512, 4) void k_ffn2(const unsigned short* __restrict__ hidden,
                                                 const unsigned short* __restrict__ w2b,
                                                 const int* __restrict__ counts,
                                                 unsigned short* __restrict__ p){
  extern __shared__ unsigned short lds[];
  int orig = blockIdx.x;                    // 468 blocks
  int xcd = orig & 7, idx = orig >> 3;
  int base = xcd < 4 ? xcd*59 : 236 + (xcd-4)*58;  // q=58, r=4 bijective
  int nw = base + idx;
  int tile  = nw % MAXT256;
  int combo = nw / MAXT256;                 // [0,12)
  int nt = combo & 3;                       // 256-col group of H
  int kh = combo >> 2;                      // K third of F
  int kb = kh*12;                           // K-tile base
  int NT = (kh == 2) ? 8 : 12;
  int e, ts_e, n_e, btot;
  EXPERT_PREFIX(tile, counts, e, ts_e, n_e, btot);
  if (tile >= btot) return;
  int row0 = (tile - ts_e)*256;
  int ebase = ts_e*256;

  int tid = threadIdx.x, lane = tid & 63, wid = tid >> 6;
  int wm = wid >> 2, wn = wid & 3;          // 2 x 4 wave grid

  const unsigned short* sA[2][2];
  const unsigned short* sB[2][2];
#pragma unroll
  for (int h=0;h<2;h++){
#pragma unroll
    for (int i=0;i<2;i++){
      int idx2 = i*512 + tid;
      int r = idx2 >> 3, seg = idx2 & 7;
      int sc = (seg ^ (r & 7))*8;
      int br = ((r>>6)<<7) | (h<<6) | (r & 63);   // interleaved A halves (bit6)
      sA[h][i] = hidden + (size_t)(ebase + row0 + br)*F_DIM + sc + kb*64;
      sB[h][i] = w2b + ((size_t)e*H_DIM + nt*256 + h*128 + r)*F_DIM + sc + kb*64;
    }
  }
  int dstb0 = wid*512;
  int dstb1 = 4096 + wid*512;

  int aoff[4][2], boff[2][2];
#pragma unroll
  for (int m=0;m<4;m++){
    int ia = wm*64 + m*16 + (lane & 15);
#pragma unroll
    for (int ks=0;ks<2;ks++)
      aoff[m][ks] = ia*128 + ((ks*64 + (lane>>4)*16) ^ ((ia & 7) << 4));
  }
#pragma unroll
  for (int n=0;n<2;n++){
    int ib = wn*32 + n*16 + (lane & 15);
#pragma unroll
    for (int ks=0;ks<2;ks++)
      boff[n][ks] = ib*128 + ((ks*64 + (lane>>4)*16) ^ ((ib & 7) << 4));
  }

  f32x4 acc[2][2][4][2];
#pragma unroll
  for (int qr=0;qr<2;qr++)
#pragma unroll
  for (int qc=0;qc<2;qc++)
#pragma unroll
  for (int m=0;m<4;m++)
#pragma unroll
  for (int n=0;n<2;n++) acc[qr][qc][m][n] = {0.f,0.f,0.f,0.f};

  bf16x8 a[4][2], bA[2][2], bB[2][2];

  KLOOP_SB(NT);

  // plain-store epilogue: p[kh][ebase+row][col] = bf16 partial
  int r16 = ((lane >> 4) & 3)*4;
  unsigned short* pk = p + (size_t)kh*MAXROWS*H_DIM;
#pragma unroll
  for (int qr=0;qr<2;qr++){
#pragma unroll
    for (int m=0;m<4;m++){
#pragma unroll
      for (int j=0;j<4;j++){
        int gr = row0 + wm*128 + qr*64 + m*16 + r16 + j;
        if (gr < n_e){
          unsigned short* pr = pk + (size_t)(ebase + gr)*H_DIM;
#pragma unroll
          for (int qc=0;qc<2;qc++){
#pragma unroll
            for (int n=0;n<2;n++){
              int col = nt*256 + qc*128 + wn*32 + n*16 + (lane & 15);
              pr[col] = f2bf(acc[qr][qc][m][n][j]);
            }
          }
        }
      }
    }
  }
}

// ------- combine: out[t] = w0*sum_kh p[kh][s0] + w1*sum_kh p[kh][s1] --------
__global__ __launch_bounds__(256) void k_comb(const unsigned short* __restrict__ p,
                                              const int* __restrict__ slotof,
                                              const float* __restrict__ topv,
                                              float* __restrict__ out){
  int t = blockIdx.x;
  int c = threadIdx.x;
  int col = c*4;
  int s0 = slotof[2*t], s1 = slotof[2*t+1];
  float w0 = topv[2*t], w1 = topv[2*t+1];
  float4 o = {0.f,0.f,0.f,0.f};
#pragma unroll
  for (int kh=0; kh<3; ++kh){
    const unsigned short* pk = p + (size_t)kh*MAXROWS*H_DIM;
    ushort4 a4 = *reinterpret_cast<const ushort4*>(pk + (size_t)s0*H_DIM + col);
    ushort4 b4 = *reinterpret_cast<const ushort4*>(pk + (size_t)s1*H_DIM + col);
    o.x += w0*bf2f(a4.x) + w1*bf2f(b4.x);
    o.y += w0*bf2f(a4.y) + w1*bf2f(b4.y);
    o.z += w0*bf2f(a4.z) + w1*bf2f(b4.z);
    o.w += w0*bf2f(a4.w) + w1*bf2f(b4.w);
  }
  reinterpret_cast<float4*>(out + (size_t)t*H_DIM)[c] = o;
}

// ---------------------------------------------------------------------------
extern "C" void kernel_launch(void* const* d_in, const int* in_sizes, int n_in,
                              void* d_out, int out_size, void* d_ws, size_t ws_size,
                              hipStream_t stream){
  const float* x  = (const float*)d_in[0];
  const float* rw = (const float*)d_in[1];
  const float* w1 = (const float*)d_in[2];
  const float* w2 = (const float*)d_in[3];
  const float* w3 = (const float*)d_in[4];
  float* out = (float*)d_out;

  char* ws = (char*)d_ws;
  size_t off = 0;
  unsigned short* xb  = (unsigned short*)(ws + off); off += (size_t)T_TOK*H_DIM*2;
  unsigned short* w1b = (unsigned short*)(ws + off); off += (size_t)E_NUM*F_DIM*H_DIM*2;
  unsigned short* w3b = (unsigned short*)(ws + off); off += (size_t)E_NUM*F_DIM*H_DIM*2;
  unsigned short* w2b = (unsigned short*)(ws + off); off += (size_t)E_NUM*H_DIM*F_DIM*2;
  unsigned short* hidden = (unsigned short*)(ws + off); off += (size_t)MAXROWS*F_DIM*2;
  int*   counts  = (int*)(ws + off); off += 64;
  int*   cursors = (int*)(ws + off); off += 64;
  int*   topi    = (int*)(ws + off); off += (size_t)T_TOK*2*4;
  float* topv    = (float*)(ws + off); off += (size_t)T_TOK*2*4;
  int*   entries = (int*)(ws + off); off += (size_t)MAXROWS*4;
  int*   slotof  = (int*)(ws + off); off += (size_t)T_TOK*2*4;
  // partials p[3][MAXROWS][H] bf16 aliased onto w1b+w3b (dead after k_ffn1)
  unsigned short* p = w1b;

  hipFuncSetAttribute((const void*)k_ffn1,
                      hipFuncAttributeMaxDynamicSharedMemorySize, 65536);
  hipFuncSetAttribute((const void*)k_ffn2,
                      hipFuncAttributeMaxDynamicSharedMemorySize, 65536);

  hipMemsetAsync(counts, 0, 128, stream);   // counts[16] + cursors[16]

  k_pre<<<128 + 2*2048, 256, 0, stream>>>(x, rw, w1, w3, w1b, w3b, xb,
                                          counts, topi, topv);
  k_fill<<<T_TOK/256, 256, 0, stream>>>(topi, counts, cursors, entries, slotof);
  k_ffn1<<<624 + 384, 512, 65536, stream>>>(xb, w1b, w3b, counts, entries,
                                            hidden, w2, w2b);
  k_ffn2<<<MAXT256*12, 512, 65536, stream>>>(hidden, w2b, counts, p);
  k_comb<<<T_TOK, 256, 0, stream>>>(p, slotof, topv, out);
}

// Round 17
// 294.242 us; speedup vs baseline: 4.4843x; 4.4843x over previous
//
#include <hip/hip_runtime.h>
#include <hip/hip_bf16.h>
#include <cstdint>

#define T_TOK 4096
#define H_DIM 1024
#define F_DIM 2048
#define E_NUM 8
#define MAXT256 39
#define MAXROWS (MAXT256*256)   // 9984 padded entry rows

typedef __attribute__((ext_vector_type(8))) short bf16x8;
typedef __attribute__((ext_vector_type(4))) float f32x4;

__device__ __forceinline__ unsigned short f2bf(float f){
  union { float f; uint32_t u; } c; c.f = f;
  uint32_t u = c.u;
  uint32_t r = (u + 0x7fffu + ((u >> 16) & 1u)) >> 16;
  return (unsigned short)r;
}
__device__ __forceinline__ float bf2f(unsigned short u){
  union { uint32_t u; float f; } c; c.u = ((uint32_t)u) << 16;
  return c.f;
}

// expert lookup from counts via unrolled prefix
#define EXPERT_PREFIX(tile, counts, e, ts_e, n_e, btot) do{ \
  btot = 0; e = 0; ts_e = 0; n_e = 0; \
  _Pragma("unroll") for (int i_=0;i_<E_NUM;i_++){ \
    int cnt_ = (counts)[i_]; \
    if ((tile) >= btot){ e = i_; ts_e = btot; n_e = cnt_; } \
    btot += (cnt_ + 255) >> 8; } }while(0)

// ---- pre-pass: router (blocks 0..127) + w1/w3 fp32->bf16 -------------------
__global__ __launch_bounds__(256) void k_pre(const float* __restrict__ x,
                                             const float* __restrict__ rw,
                                             const float* __restrict__ w1,
                                             const float* __restrict__ w3,
                                             unsigned short* __restrict__ w1b,
                                             unsigned short* __restrict__ w3b,
                                             unsigned short* __restrict__ xb,
                                             int* __restrict__ counts,
                                             int* __restrict__ topi,
                                             float* __restrict__ topv){
  __shared__ float lrw[E_NUM][8][132];
  __shared__ int hist[E_NUM];
  int tid = threadIdx.x;
  if (blockIdx.x < 128){
    if (tid < E_NUM) hist[tid] = 0;
    for (int i = tid; i < E_NUM*H_DIM/4; i += 256){
      int idx = i*4;
      int e = idx >> 10, rem = idx & 1023, c = rem >> 7, j = rem & 127;
      float4 v = reinterpret_cast<const float4*>(rw)[i];
      *reinterpret_cast<float4*>(&lrw[e][c][j]) = v;
    }
    __syncthreads();
    int t = blockIdx.x*32 + (tid >> 3);
    int c = tid & 7;
    const float4* xr = reinterpret_cast<const float4*>(x + (size_t)t*H_DIM + c*128);
    ushort4* xw = reinterpret_cast<ushort4*>(xb + (size_t)t*H_DIM + c*128);
    double acc[E_NUM];
#pragma unroll
    for (int e=0;e<E_NUM;e++) acc[e] = 0.0;
    for (int j4=0; j4<32; ++j4){
      float4 v = xr[j4];
      ushort4 o;
      o.x = f2bf(v.x); o.y = f2bf(v.y); o.z = f2bf(v.z); o.w = f2bf(v.w);
      xw[j4] = o;
#pragma unroll
      for (int e=0;e<E_NUM;e++){
        float4 r = *reinterpret_cast<const float4*>(&lrw[e][c][j4*4]);
        acc[e] += (double)v.x*(double)r.x + (double)v.y*(double)r.y
                + (double)v.z*(double)r.z + (double)v.w*(double)r.w;
      }
    }
#pragma unroll
    for (int e=0;e<E_NUM;e++){
      double s = acc[e];
      s += __shfl_xor(s, 1, 64);
      s += __shfl_xor(s, 2, 64);
      s += __shfl_xor(s, 4, 64);
      acc[e] = s;
    }
    if (c == 0){
      int i0 = 0; double v0 = acc[0];
      for (int e=1;e<E_NUM;e++) if (acc[e] > v0){ v0 = acc[e]; i0 = e; }
      int i1 = -1; double v1 = -1e300;
      for (int e=0;e<E_NUM;e++) if (e != i0 && acc[e] > v1){ v1 = acc[e]; i1 = e; }
      float w0 = 1.0f/(1.0f + expf((float)(v1 - v0)));
      topi[2*t] = i0; topi[2*t+1] = i1;
      topv[2*t] = w0; topv[2*t+1] = 1.0f - w0;
      atomicAdd(&hist[i0], 1); atomicAdd(&hist[i1], 1);
    }
    __syncthreads();
    if (tid < E_NUM && hist[tid]) atomicAdd(&counts[tid], hist[tid]);
  } else {
    int b2 = blockIdx.x - 128;
    int seg = b2 >> 11;
    int b   = b2 & 2047;
    const float* s = seg==0 ? w1 : w3;
    unsigned short* d = seg==0 ? w1b : w3b;
    const int n4 = E_NUM*F_DIM*H_DIM/4;
    for (int i = b*256 + tid; i < n4; i += 2048*256){
      float4 v = reinterpret_cast<const float4*>(s)[i];
      ushort4 o;
      o.x = f2bf(v.x); o.y = f2bf(v.y); o.z = f2bf(v.z); o.w = f2bf(v.w);
      reinterpret_cast<ushort4*>(d)[i] = o;
    }
  }
}

// ---------------- fill grouped entry lists + inverse map --------------------
__global__ __launch_bounds__(256) void k_fill(const int* __restrict__ topi,
                                              const int* __restrict__ counts,
                                              int* __restrict__ cursors,
                                              int* __restrict__ entries,
                                              int* __restrict__ slotof){
  __shared__ int ts[E_NUM];
  if (threadIdx.x == 0){
    int b = 0;
    for (int e=0;e<E_NUM;e++){ ts[e] = b; b += (counts[e] + 255) >> 8; }
  }
  __syncthreads();
  int t = blockIdx.x*256 + threadIdx.x;
  if (t >= T_TOK) return;
#pragma unroll
  for (int k=0;k<2;k++){
    int e = topi[2*t+k];
    int pos = atomicAdd(&cursors[e], 1);
    int slot = ts[e]*256 + pos;
    entries[slot] = 2*t + k;
    slotof[2*t+k] = slot;
  }
}

// ---------------- staging macro ---------------------------------------------
#define GLD(src, dst_us) __builtin_amdgcn_global_load_lds( \
  (const __attribute__((address_space(1))) unsigned int*)(src), \
  (__attribute__((address_space(3))) unsigned int*)(lds + (dst_us)), 16, 0, 0)

// ---------------- 256x256 SINGLE-BUFFER K-loop (2 blocks/CU via LDS) --------
// LDS = 64 KiB: parts 0=A0,1=A1,2=B0,3=B1 (16 KiB each). Per K-tile:
// syncthreads (readers done) -> stage 8 gload_lds -> syncthreads (implicit
// vmcnt(0)+lgkmcnt(0) drain) -> ds_read frags + 64 MFMA, compiler-scheduled.
// Cross-block overlap (2 blocks/CU from 64KB LDS, natural VGPR ~120) hides
// the drain (m97/m114 mechanism).

#define STG1(X, s0, s1, kS) do{ \
  GLD((s0) + (kS)*64, (X)*8192 + dstb0); \
  GLD((s1) + (kS)*64, (X)*8192 + dstb1); }while(0)

#define LDA1(QR) do{ const char* p_ = (const char*)lds + (QR)*16384; \
  _Pragma("unroll") for (int m_=0;m_<4;m_++) \
  _Pragma("unroll") for (int ks_=0;ks_<2;ks_++) \
    a[m_][ks_] = *(const bf16x8*)(p_ + aoff[m_][ks_]); }while(0)

#define LDB1(QC, breg) do{ const char* p_ = (const char*)lds + (2+(QC))*16384; \
  _Pragma("unroll") for (int n_=0;n_<2;n_++) \
  _Pragma("unroll") for (int ks_=0;ks_<2;ks_++) \
    breg[n_][ks_] = *(const bf16x8*)(p_ + boff[n_][ks_]); }while(0)

#define MM(QR, QC, breg) do{ \
  _Pragma("unroll") for (int m_=0;m_<4;m_++) \
  _Pragma("unroll") for (int n_=0;n_<2;n_++) \
  _Pragma("unroll") for (int ks_=0;ks_<2;ks_++) \
    acc[QR][QC][m_][n_] = __builtin_amdgcn_mfma_f32_16x16x32_bf16(a[m_][ks_], breg[n_][ks_], acc[QR][QC][m_][n_], 0,0,0); }while(0)

#define KLOOP_SB(NTILES) do{ \
  _Pragma("unroll 1") for (int T=0; T<(NTILES); ++T){ \
    __syncthreads(); \
    STG1(0, sA[0][0], sA[0][1], T); \
    STG1(2, sB[0][0], sB[0][1], T); \
    STG1(3, sB[1][0], sB[1][1], T); \
    STG1(1, sA[1][0], sA[1][1], T); \
    __syncthreads(); \
    LDA1(0); LDB1(0,bA); LDB1(1,bB); \
    MM(0,0,bA); MM(0,1,bB); \
    LDA1(1); \
    MM(1,0,bA); MM(1,1,bB); \
  } \
}while(0)

// ---------------- phase 1: 256x256 grouped GEMM + SiLU ----------------------
// blocks >= 624 convert w2 fp32->bf16 (dispatch last -> fill straggler slots)
__global__ __launch_bounds__(512) void k_ffn1(const unsigned short* __restrict__ xb,
                                              const unsigned short* __restrict__ w1b,
                                              const unsigned short* __restrict__ w3b,
                                              const int* __restrict__ counts,
                                              const int* __restrict__ entries,
                                              unsigned short* __restrict__ hidden,
                                              const float* __restrict__ w2,
                                              unsigned short* __restrict__ w2b){
  extern __shared__ unsigned short lds[];
  int flat = blockIdx.x;
  if (flat >= 624){
    int b2 = flat - 624;                    // [0,384): w2 convert, 512 threads
    const int n4 = E_NUM*F_DIM*H_DIM/4;
    for (int i = b2*512 + (int)threadIdx.x; i < n4; i += 384*512){
      float4 v = reinterpret_cast<const float4*>(w2)[i];
      ushort4 o;
      o.x = f2bf(v.x); o.y = f2bf(v.y); o.z = f2bf(v.z); o.w = f2bf(v.w);
      reinterpret_cast<ushort4*>(w2b)[i] = o;
    }
    return;
  }
  int nw = (flat & 7)*78 + (flat >> 3);     // 624 = 8*78 bijective XCD chunking
  int tile = nw % MAXT256;
  int nt   = nw / MAXT256;
  int e, ts_e, n_e, btot;
  EXPERT_PREFIX(tile, counts, e, ts_e, n_e, btot);
  if (tile >= btot) return;
  int row0 = (tile - ts_e)*256;
  int ebase = ts_e*256;

  int tid = threadIdx.x, lane = tid & 63, wid = tid >> 6;
  int wm = wid >> 2, wn = wid & 3;          // 2 x 4 wave grid

  const unsigned short* sA[2][2];
  const unsigned short* sB[2][2];
#pragma unroll
  for (int h=0;h<2;h++){
#pragma unroll
    for (int i=0;i<2;i++){
      int idx = i*512 + tid;
      int r = idx >> 3, seg = idx & 7;
      int sc = (seg ^ (r & 7))*8;
      int br = ((r>>6)<<7) | (h<<6) | (r & 63);   // interleaved A halves (bit6)
      int rr = row0 + br; rr = rr < n_e ? rr : (n_e - 1);
      int tokr = entries[ebase + rr] >> 1;
      sA[h][i] = xb + (size_t)tokr*H_DIM + sc;
      const unsigned short* w = h ? w3b : w1b;    // B part2=w1(gate), part3=w3(up)
      sB[h][i] = w + ((size_t)e*F_DIM + nt*128 + r)*H_DIM + sc;
    }
  }
  int dstb0 = wid*512;
  int dstb1 = 4096 + wid*512;

  int aoff[4][2], boff[2][2];
#pragma unroll
  for (int m=0;m<4;m++){
    int ia = wm*64 + m*16 + (lane & 15);
#pragma unroll
    for (int ks=0;ks<2;ks++)
      aoff[m][ks] = ia*128 + ((ks*64 + (lane>>4)*16) ^ ((ia & 7) << 4));
  }
#pragma unroll
  for (int n=0;n<2;n++){
    int ib = wn*32 + n*16 + (lane & 15);
#pragma unroll
    for (int ks=0;ks<2;ks++)
      boff[n][ks] = ib*128 + ((ks*64 + (lane>>4)*16) ^ ((ib & 7) << 4));
  }

  f32x4 acc[2][2][4][2];
#pragma unroll
  for (int qr=0;qr<2;qr++)
#pragma unroll
  for (int qc=0;qc<2;qc++)
#pragma unroll
  for (int m=0;m<4;m++)
#pragma unroll
  for (int n=0;n<2;n++) acc[qr][qc][m][n] = {0.f,0.f,0.f,0.f};

  bf16x8 a[4][2], bA[2][2], bB[2][2];

  KLOOP_SB(16);

  // SiLU epilogue: gate=acc[qr][0], up=acc[qr][1]
  int r16 = ((lane >> 4) & 3)*4;
#pragma unroll
  for (int qr=0;qr<2;qr++){
#pragma unroll
    for (int m=0;m<4;m++){
#pragma unroll
      for (int j=0;j<4;j++){
        int br = wm*128 + qr*64 + m*16 + r16 + j;
        if (row0 + br < n_e){
          size_t rowbase = (size_t)(ebase + row0 + br)*F_DIM + nt*128 + wn*32;
#pragma unroll
          for (int n=0;n<2;n++){
            float g = acc[qr][0][m][n][j];
            float u = acc[qr][1][m][n][j];
            float h = (g / (1.f + __expf(-g))) * u;
            hidden[rowbase + n*16 + (lane & 15)] = f2bf(h);
          }
        }
      }
    }
  }
}

// ---------------- phase 2: 256x256 grouped GEMM, K-split x3, bf16 partials --
// Grid 468 = 39 x (4 nt x 3 kh). K-ranges {12,12,8}. Partials p[kh][slot][H]
// bf16 plain stores (no atomics), aliased onto dead w1b/w3b (61.3 MB).
__global__ __launch_bounds__(512) void k_ffn2(const unsigned short* __restrict__ hidden,
                                              const unsigned short* __restrict__ w2b,
                                              const int* __restrict__ counts,
                                              unsigned short* __restrict__ p){
  extern __shared__ unsigned short lds[];
  int orig = blockIdx.x;                    // 468 blocks
  int xcd = orig & 7, idx = orig >> 3;
  int base = xcd < 4 ? xcd*59 : 236 + (xcd-4)*58;  // q=58, r=4 bijective
  int nw = base + idx;
  int tile  = nw % MAXT256;
  int combo = nw / MAXT256;                 // [0,12)
  int nt = combo & 3;                       // 256-col group of H
  int kh = combo >> 2;                      // K third of F
  int kb = kh*12;                           // K-tile base
  int NT = (kh == 2) ? 8 : 12;
  int e, ts_e, n_e, btot;
  EXPERT_PREFIX(tile, counts, e, ts_e, n_e, btot);
  if (tile >= btot) return;
  int row0 = (tile - ts_e)*256;
  int ebase = ts_e*256;

  int tid = threadIdx.x, lane = tid & 63, wid = tid >> 6;
  int wm = wid >> 2, wn = wid & 3;          // 2 x 4 wave grid

  const unsigned short* sA[2][2];
  const unsigned short* sB[2][2];
#pragma unroll
  for (int h=0;h<2;h++){
#pragma unroll
    for (int i=0;i<2;i++){
      int idx2 = i*512 + tid;
      int r = idx2 >> 3, seg = idx2 & 7;
      int sc = (seg ^ (r & 7))*8;
      int br = ((r>>6)<<7) | (h<<6) | (r & 63);   // interleaved A halves (bit6)
      sA[h][i] = hidden + (size_t)(ebase + row0 + br)*F_DIM + sc + kb*64;
      sB[h][i] = w2b + ((size_t)e*H_DIM + nt*256 + h*128 + r)*F_DIM + sc + kb*64;
    }
  }
  int dstb0 = wid*512;
  int dstb1 = 4096 + wid*512;

  int aoff[4][2], boff[2][2];
#pragma unroll
  for (int m=0;m<4;m++){
    int ia = wm*64 + m*16 + (lane & 15);
#pragma unroll
    for (int ks=0;ks<2;ks++)
      aoff[m][ks] = ia*128 + ((ks*64 + (lane>>4)*16) ^ ((ia & 7) << 4));
  }
#pragma unroll
  for (int n=0;n<2;n++){
    int ib = wn*32 + n*16 + (lane & 15);
#pragma unroll
    for (int ks=0;ks<2;ks++)
      boff[n][ks] = ib*128 + ((ks*64 + (lane>>4)*16) ^ ((ib & 7) << 4));
  }

  f32x4 acc[2][2][4][2];
#pragma unroll
  for (int qr=0;qr<2;qr++)
#pragma unroll
  for (int qc=0;qc<2;qc++)
#pragma unroll
  for (int m=0;m<4;m++)
#pragma unroll
  for (int n=0;n<2;n++) acc[qr][qc][m][n] = {0.f,0.f,0.f,0.f};

  bf16x8 a[4][2], bA[2][2], bB[2][2];

  KLOOP_SB(NT);

  // plain-store epilogue: p[kh][ebase+row][col] = bf16 partial
  int r16 = ((lane >> 4) & 3)*4;
  unsigned short* pk = p + (size_t)kh*MAXROWS*H_DIM;
#pragma unroll
  for (int qr=0;qr<2;qr++){
#pragma unroll
    for (int m=0;m<4;m++){
#pragma unroll
      for (int j=0;j<4;j++){
        int gr = row0 + wm*128 + qr*64 + m*16 + r16 + j;
        if (gr < n_e){
          unsigned short* pr = pk + (size_t)(ebase + gr)*H_DIM;
#pragma unroll
          for (int qc=0;qc<2;qc++){
#pragma unroll
            for (int n=0;n<2;n++){
              int col = nt*256 + qc*128 + wn*32 + n*16 + (lane & 15);
              pr[col] = f2bf(acc[qr][qc][m][n][j]);
            }
          }
        }
      }
    }
  }
}

// ------- combine: out[t] = w0*sum_kh p[kh][s0] + w1*sum_kh p[kh][s1] --------
__global__ __launch_bounds__(256) void k_comb(const unsigned short* __restrict__ p,
                                              const int* __restrict__ slotof,
                                              const float* __restrict__ topv,
                                              float* __restrict__ out){
  int t = blockIdx.x;
  int c = threadIdx.x;
  int col = c*4;
  int s0 = slotof[2*t], s1 = slotof[2*t+1];
  float w0 = topv[2*t], w1 = topv[2*t+1];
  float4 o = {0.f,0.f,0.f,0.f};
#pragma unroll
  for (int kh=0; kh<3; ++kh){
    const unsigned short* pk = p + (size_t)kh*MAXROWS*H_DIM;
    ushort4 a4 = *reinterpret_cast<const ushort4*>(pk + (size_t)s0*H_DIM + col);
    ushort4 b4 = *reinterpret_cast<const ushort4*>(pk + (size_t)s1*H_DIM + col);
    o.x += w0*bf2f(a4.x) + w1*bf2f(b4.x);
    o.y += w0*bf2f(a4.y) + w1*bf2f(b4.y);
    o.z += w0*bf2f(a4.z) + w1*bf2f(b4.z);
    o.w += w0*bf2f(a4.w) + w1*bf2f(b4.w);
  }
  reinterpret_cast<float4*>(out + (size_t)t*H_DIM)[c] = o;
}

// ---------------------------------------------------------------------------
extern "C" void kernel_launch(void* const* d_in, const int* in_sizes, int n_in,
                              void* d_out, int out_size, void* d_ws, size_t ws_size,
                              hipStream_t stream){
  const float* x  = (const float*)d_in[0];
  const float* rw = (const float*)d_in[1];
  const float* w1 = (const float*)d_in[2];
  const float* w2 = (const float*)d_in[3];
  const float* w3 = (const float*)d_in[4];
  float* out = (float*)d_out;

  char* ws = (char*)d_ws;
  size_t off = 0;
  unsigned short* xb  = (unsigned short*)(ws + off); off += (size_t)T_TOK*H_DIM*2;
  unsigned short* w1b = (unsigned short*)(ws + off); off += (size_t)E_NUM*F_DIM*H_DIM*2;
  unsigned short* w3b = (unsigned short*)(ws + off); off += (size_t)E_NUM*F_DIM*H_DIM*2;
  unsigned short* w2b = (unsigned short*)(ws + off); off += (size_t)E_NUM*H_DIM*F_DIM*2;
  unsigned short* hidden = (unsigned short*)(ws + off); off += (size_t)MAXROWS*F_DIM*2;
  int*   counts  = (int*)(ws + off); off += 64;
  int*   cursors = (int*)(ws + off); off += 64;
  int*   topi    = (int*)(ws + off); off += (size_t)T_TOK*2*4;
  float* topv    = (float*)(ws + off); off += (size_t)T_TOK*2*4;
  int*   entries = (int*)(ws + off); off += (size_t)MAXROWS*4;
  int*   slotof  = (int*)(ws + off); off += (size_t)T_TOK*2*4;
  // partials p[3][MAXROWS][H] bf16 aliased onto w1b+w3b (dead after k_ffn1)
  unsigned short* p = w1b;

  hipFuncSetAttribute((const void*)k_ffn1,
                      hipFuncAttributeMaxDynamicSharedMemorySize, 65536);
  hipFuncSetAttribute((const void*)k_ffn2,
                      hipFuncAttributeMaxDynamicSharedMemorySize, 65536);

  hipMemsetAsync(counts, 0, 128, stream);   // counts[16] + cursors[16]

  k_pre<<<128 + 2*2048, 256, 0, stream>>>(x, rw, w1, w3, w1b, w3b, xb,
                                          counts, topi, topv);
  k_fill<<<T_TOK/256, 256, 0, stream>>>(topi, counts, cursors, entries, slotof);
  k_ffn1<<<624 + 384, 512, 65536, stream>>>(xb, w1b, w3b, counts, entries,
                                            hidden, w2, w2b);
  k_ffn2<<<MAXT256*12, 512, 65536, stream>>>(hidden, w2b, counts, p);
  k_comb<<<T_TOK, 256, 0, stream>>>(p, slotof, topv, out);
}

// Round 18
// 259.027 us; speedup vs baseline: 5.0939x; 1.1360x over previous
//
#include <hip/hip_runtime.h>
#include <hip/hip_bf16.h>
#include <cstdint>

#define T_TOK 4096
#define H_DIM 1024
#define F_DIM 2048
#define E_NUM 8
#define MAXT256 39
#define MAXROWS (MAXT256*256)   // 9984 padded entry rows

typedef __attribute__((ext_vector_type(8))) short bf16x8;
typedef __attribute__((ext_vector_type(4))) float f32x4;

__device__ __forceinline__ unsigned short f2bf(float f){
  union { float f; uint32_t u; } c; c.f = f;
  uint32_t u = c.u;
  uint32_t r = (u + 0x7fffu + ((u >> 16) & 1u)) >> 16;
  return (unsigned short)r;
}
__device__ __forceinline__ float bf2f(unsigned short u){
  union { uint32_t u; float f; } c; c.u = ((uint32_t)u) << 16;
  return c.f;
}

// expert lookup from counts via unrolled prefix
#define EXPERT_PREFIX(tile, counts, e, ts_e, n_e, btot) do{ \
  btot = 0; e = 0; ts_e = 0; n_e = 0; \
  _Pragma("unroll") for (int i_=0;i_<E_NUM;i_++){ \
    int cnt_ = (counts)[i_]; \
    if ((tile) >= btot){ e = i_; ts_e = btot; n_e = cnt_; } \
    btot += (cnt_ + 255) >> 8; } }while(0)

// ---- pre-pass: router (blocks 0..127) + w1/w3 fp32->bf16 -------------------
__global__ __launch_bounds__(256) void k_pre(const float* __restrict__ x,
                                             const float* __restrict__ rw,
                                             const float* __restrict__ w1,
                                             const float* __restrict__ w3,
                                             unsigned short* __restrict__ w1b,
                                             unsigned short* __restrict__ w3b,
                                             unsigned short* __restrict__ xb,
                                             int* __restrict__ counts,
                                             int* __restrict__ topi,
                                             float* __restrict__ topv){
  __shared__ float lrw[E_NUM][8][132];
  __shared__ int hist[E_NUM];
  int tid = threadIdx.x;
  if (blockIdx.x < 128){
    if (tid < E_NUM) hist[tid] = 0;
    for (int i = tid; i < E_NUM*H_DIM/4; i += 256){
      int idx = i*4;
      int e = idx >> 10, rem = idx & 1023, c = rem >> 7, j = rem & 127;
      float4 v = reinterpret_cast<const float4*>(rw)[i];
      *reinterpret_cast<float4*>(&lrw[e][c][j]) = v;
    }
    __syncthreads();
    int t = blockIdx.x*32 + (tid >> 3);
    int c = tid & 7;
    const float4* xr = reinterpret_cast<const float4*>(x + (size_t)t*H_DIM + c*128);
    ushort4* xw = reinterpret_cast<ushort4*>(xb + (size_t)t*H_DIM + c*128);
    double acc[E_NUM];
#pragma unroll
    for (int e=0;e<E_NUM;e++) acc[e] = 0.0;
    for (int j4=0; j4<32; ++j4){
      float4 v = xr[j4];
      ushort4 o;
      o.x = f2bf(v.x); o.y = f2bf(v.y); o.z = f2bf(v.z); o.w = f2bf(v.w);
      xw[j4] = o;
#pragma unroll
      for (int e=0;e<E_NUM;e++){
        float4 r = *reinterpret_cast<const float4*>(&lrw[e][c][j4*4]);
        acc[e] += (double)v.x*(double)r.x + (double)v.y*(double)r.y
                + (double)v.z*(double)r.z + (double)v.w*(double)r.w;
      }
    }
#pragma unroll
    for (int e=0;e<E_NUM;e++){
      double s = acc[e];
      s += __shfl_xor(s, 1, 64);
      s += __shfl_xor(s, 2, 64);
      s += __shfl_xor(s, 4, 64);
      acc[e] = s;
    }
    if (c == 0){
      int i0 = 0; double v0 = acc[0];
      for (int e=1;e<E_NUM;e++) if (acc[e] > v0){ v0 = acc[e]; i0 = e; }
      int i1 = -1; double v1 = -1e300;
      for (int e=0;e<E_NUM;e++) if (e != i0 && acc[e] > v1){ v1 = acc[e]; i1 = e; }
      float w0 = 1.0f/(1.0f + expf((float)(v1 - v0)));
      topi[2*t] = i0; topi[2*t+1] = i1;
      topv[2*t] = w0; topv[2*t+1] = 1.0f - w0;
      atomicAdd(&hist[i0], 1); atomicAdd(&hist[i1], 1);
    }
    __syncthreads();
    if (tid < E_NUM && hist[tid]) atomicAdd(&counts[tid], hist[tid]);
  } else {
    int b2 = blockIdx.x - 128;
    int seg = b2 >> 11;
    int b   = b2 & 2047;
    const float* s = seg==0 ? w1 : w3;
    unsigned short* d = seg==0 ? w1b : w3b;
    const int n4 = E_NUM*F_DIM*H_DIM/4;
    for (int i = b*256 + tid; i < n4; i += 2048*256){
      float4 v = reinterpret_cast<const float4*>(s)[i];
      ushort4 o;
      o.x = f2bf(v.x); o.y = f2bf(v.y); o.z = f2bf(v.z); o.w = f2bf(v.w);
      reinterpret_cast<ushort4*>(d)[i] = o;
    }
  }
}

// ---------------- fill grouped entry lists + inverse map --------------------
__global__ __launch_bounds__(256) void k_fill(const int* __restrict__ topi,
                                              const int* __restrict__ counts,
                                              int* __restrict__ cursors,
                                              int* __restrict__ entries,
                                              int* __restrict__ slotof){
  __shared__ int ts[E_NUM];
  if (threadIdx.x == 0){
    int b = 0;
    for (int e=0;e<E_NUM;e++){ ts[e] = b; b += (counts[e] + 255) >> 8; }
  }
  __syncthreads();
  int t = blockIdx.x*256 + threadIdx.x;
  if (t >= T_TOK) return;
#pragma unroll
  for (int k=0;k<2;k++){
    int e = topi[2*t+k];
    int pos = atomicAdd(&cursors[e], 1);
    int slot = ts[e]*256 + pos;
    entries[slot] = 2*t + k;
    slotof[2*t+k] = slot;
  }
}

// ---------------- shared sync / staging macros ------------------------------
#define GLD(src, dst_us) __builtin_amdgcn_global_load_lds( \
  (const __attribute__((address_space(1))) unsigned int*)(src), \
  (__attribute__((address_space(3))) unsigned int*)(lds + (dst_us)), 16, 0, 0)

#define VMW(N) asm volatile("s_waitcnt vmcnt(" #N ")" ::: "memory")
#define BARS do{ __builtin_amdgcn_s_barrier(); __builtin_amdgcn_sched_barrier(0); }while(0)
#define MMGO do{ asm volatile("s_waitcnt lgkmcnt(0)" ::: "memory"); \
  __builtin_amdgcn_sched_barrier(0); __builtin_amdgcn_s_setprio(1); }while(0)
#define MMEND __builtin_amdgcn_s_setprio(0)

// ---------------- 256x256 3-phase K-loop (measured-best cadence) ------------
// Works for any EVEN runtime NTILES (drain epilogue reads buf1).
#define STG(X, s0, s1, dbS, kS) do{ \
  GLD((s0) + (kS)*64, (dbS)*32768 + (X)*8192 + dstb0); \
  GLD((s1) + (kS)*64, (dbS)*32768 + (X)*8192 + dstb1); }while(0)

#define LDA(db, QR) do{ const char* p_ = (const char*)lds + ((db)*4 + (QR))*16384; \
  _Pragma("unroll") for (int m_=0;m_<4;m_++) \
  _Pragma("unroll") for (int ks_=0;ks_<2;ks_++) \
    a[m_][ks_] = *(const bf16x8*)(p_ + aoff[m_][ks_]); }while(0)

#define LDB(db, QC, breg) do{ const char* p_ = (const char*)lds + ((db)*4 + 2 + (QC))*16384; \
  _Pragma("unroll") for (int n_=0;n_<2;n_++) \
  _Pragma("unroll") for (int ks_=0;ks_<2;ks_++) \
    breg[n_][ks_] = *(const bf16x8*)(p_ + boff[n_][ks_]); }while(0)

#define MM(QR, QC, breg) do{ \
  _Pragma("unroll") for (int m_=0;m_<4;m_++) \
  _Pragma("unroll") for (int n_=0;n_<2;n_++) \
  _Pragma("unroll") for (int ks_=0;ks_<2;ks_++) \
    acc[QR][QC][m_][n_] = __builtin_amdgcn_mfma_f32_16x16x32_bf16(a[m_][ks_], breg[n_][ks_], acc[QR][QC][m_][n_], 0,0,0); }while(0)

#define KLOOP(NTILES) do{ \
  STG(0, sA[0][0], sA[0][1], 0, 0); \
  STG(2, sB[0][0], sB[0][1], 0, 0); \
  STG(3, sB[1][0], sB[1][1], 0, 0); \
  STG(1, sA[1][0], sA[1][1], 0, 0); \
  for (int T=0; T<(NTILES)-1; ++T){ \
    int db = T & 1, dbS = db ^ 1, kS = T + 1; \
    VMW(4); BARS; \
    if (db == 0){ LDA(0,0); LDB(0,0,bA); } else { LDA(1,0); LDB(1,0,bA); } \
    STG(0, sA[0][0], sA[0][1], dbS, kS); \
    STG(2, sB[0][0], sB[0][1], dbS, kS); \
    MMGO; MM(0,0,bA); MMEND; \
    VMW(6); BARS; \
    if (db == 0){ LDB(0,1,bB); } else { LDB(1,1,bB); } \
    STG(3, sB[1][0], sB[1][1], dbS, kS); \
    STG(1, sA[1][0], sA[1][1], dbS, kS); \
    MMGO; MM(0,1,bB); MMEND; \
    VMW(8); BARS; \
    if (db == 0){ LDA(0,1); } else { LDA(1,1); } \
    MMGO; MM(1,0,bA); MM(1,1,bB); MMEND; \
  } \
  VMW(4); BARS; LDA(1,0); LDB(1,0,bA); MMGO; MM(0,0,bA); MMEND; \
  VMW(2); BARS; LDB(1,1,bB);           MMGO; MM(0,1,bB); MMEND; \
  VMW(0); BARS; LDA(1,1);              MMGO; MM(1,0,bA); MM(1,1,bB); MMEND; }while(0)

// ---------------- phase 1: 256x256 grouped GEMM + SiLU ----------------------
// blocks >= 624 convert w2 fp32->bf16 (dispatch last -> fill straggler round)
__global__ __launch_bounds__(512) void k_ffn1(const unsigned short* __restrict__ xb,
                                              const unsigned short* __restrict__ w1b,
                                              const unsigned short* __restrict__ w3b,
                                              const int* __restrict__ counts,
                                              const int* __restrict__ entries,
                                              unsigned short* __restrict__ hidden,
                                              const float* __restrict__ w2,
                                              unsigned short* __restrict__ w2b){
  extern __shared__ unsigned short lds[];
  int flat = blockIdx.x;
  if (flat >= 624){
    int b2 = flat - 624;                    // [0,384): w2 convert
    const int n4 = E_NUM*F_DIM*H_DIM/4;
    for (int i = b2*512 + (int)threadIdx.x; i < n4; i += 384*512){
      float4 v = reinterpret_cast<const float4*>(w2)[i];
      ushort4 o;
      o.x = f2bf(v.x); o.y = f2bf(v.y); o.z = f2bf(v.z); o.w = f2bf(v.w);
      reinterpret_cast<ushort4*>(w2b)[i] = o;
    }
    return;
  }
  int nw = (flat & 7)*78 + (flat >> 3);     // 624 = 8*78 bijective XCD chunking
  int tile = nw % MAXT256;
  int nt   = nw / MAXT256;
  int e, ts_e, n_e, btot;
  EXPERT_PREFIX(tile, counts, e, ts_e, n_e, btot);
  if (tile >= btot) return;
  int row0 = (tile - ts_e)*256;
  int ebase = ts_e*256;

  int tid = threadIdx.x, lane = tid & 63, wid = tid >> 6;
  int wm = wid >> 2, wn = wid & 3;          // 2 x 4 wave grid

  const unsigned short* sA[2][2];
  const unsigned short* sB[2][2];
#pragma unroll
  for (int h=0;h<2;h++){
#pragma unroll
    for (int i=0;i<2;i++){
      int idx = i*512 + tid;
      int r = idx >> 3, seg = idx & 7;
      int sc = (seg ^ (r & 7))*8;
      int br = ((r>>6)<<7) | (h<<6) | (r & 63);   // interleaved A halves (bit6)
      int rr = row0 + br; rr = rr < n_e ? rr : (n_e - 1);
      int tokr = entries[ebase + rr] >> 1;
      sA[h][i] = xb + (size_t)tokr*H_DIM + sc;
      const unsigned short* w = h ? w3b : w1b;    // B part2=w1(gate), part3=w3(up)
      sB[h][i] = w + ((size_t)e*F_DIM + nt*128 + r)*H_DIM + sc;
    }
  }
  int dstb0 = wid*512;
  int dstb1 = 4096 + wid*512;

  int aoff[4][2], boff[2][2];
#pragma unroll
  for (int m=0;m<4;m++){
    int ia = wm*64 + m*16 + (lane & 15);
#pragma unroll
    for (int ks=0;ks<2;ks++)
      aoff[m][ks] = ia*128 + ((ks*64 + (lane>>4)*16) ^ ((ia & 7) << 4));
  }
#pragma unroll
  for (int n=0;n<2;n++){
    int ib = wn*32 + n*16 + (lane & 15);
#pragma unroll
    for (int ks=0;ks<2;ks++)
      boff[n][ks] = ib*128 + ((ks*64 + (lane>>4)*16) ^ ((ib & 7) << 4));
  }

  f32x4 acc[2][2][4][2];
#pragma unroll
  for (int qr=0;qr<2;qr++)
#pragma unroll
  for (int qc=0;qc<2;qc++)
#pragma unroll
  for (int m=0;m<4;m++)
#pragma unroll
  for (int n=0;n<2;n++) acc[qr][qc][m][n] = {0.f,0.f,0.f,0.f};

  bf16x8 a[4][2], bA[2][2], bB[2][2];

  KLOOP(16);

  // SiLU epilogue: gate=acc[qr][0], up=acc[qr][1]
  int r16 = ((lane >> 4) & 3)*4;
#pragma unroll
  for (int qr=0;qr<2;qr++){
#pragma unroll
    for (int m=0;m<4;m++){
#pragma unroll
      for (int j=0;j<4;j++){
        int br = wm*128 + qr*64 + m*16 + r16 + j;
        if (row0 + br < n_e){
          size_t rowbase = (size_t)(ebase + row0 + br)*F_DIM + nt*128 + wn*32;
#pragma unroll
          for (int n=0;n<2;n++){
            float g = acc[qr][0][m][n][j];
            float u = acc[qr][1][m][n][j];
            float h = (g / (1.f + __expf(-g))) * u;
            hidden[rowbase + n*16 + (lane & 15)] = f2bf(h);
          }
        }
      }
    }
  }
}

// ---------------- phase 2: 256x256 grouped GEMM, K-split x3, bf16 partials --
// Grid 468 = 39 x (4 nt x 3 kh). K-ranges {12,12,8} K-tiles (all even).
// Per-(nt,kh) w2 slice ~3.1 MB -> L2-resident. Partials p[kh][slot][H] bf16,
// plain coalesced stores (no atomics), aliased onto dead w1b/w3b (61.3 MB).
__global__ __launch_bounds__(512) void k_ffn2(const unsigned short* __restrict__ hidden,
                                              const unsigned short* __restrict__ w2b,
                                              const int* __restrict__ counts,
                                              unsigned short* __restrict__ p){
  extern __shared__ unsigned short lds[];
  int orig = blockIdx.x;                    // 468 blocks
  int xcd = orig & 7, idx = orig >> 3;
  int base = xcd < 4 ? xcd*59 : 236 + (xcd-4)*58;  // q=58, r=4 bijective
  int nw = base + idx;
  int tile  = nw % MAXT256;
  int combo = nw / MAXT256;                 // [0,12)
  int nt = combo & 3;                       // 256-col group of H
  int kh = combo >> 2;                      // K third of F
  int kb = kh*12;                           // K-tile base
  int NT = (kh == 2) ? 8 : 12;              // even
  int e, ts_e, n_e, btot;
  EXPERT_PREFIX(tile, counts, e, ts_e, n_e, btot);
  if (tile >= btot) return;
  int row0 = (tile - ts_e)*256;
  int ebase = ts_e*256;

  int tid = threadIdx.x, lane = tid & 63, wid = tid >> 6;
  int wm = wid >> 2, wn = wid & 3;          // 2 x 4 wave grid

  const unsigned short* sA[2][2];
  const unsigned short* sB[2][2];
#pragma unroll
  for (int h=0;h<2;h++){
#pragma unroll
    for (int i=0;i<2;i++){
      int idx2 = i*512 + tid;
      int r = idx2 >> 3, seg = idx2 & 7;
      int sc = (seg ^ (r & 7))*8;
      int br = ((r>>6)<<7) | (h<<6) | (r & 63);   // interleaved A halves (bit6)
      sA[h][i] = hidden + (size_t)(ebase + row0 + br)*F_DIM + sc + kb*64;
      sB[h][i] = w2b + ((size_t)e*H_DIM + nt*256 + h*128 + r)*F_DIM + sc + kb*64;
    }
  }
  int dstb0 = wid*512;
  int dstb1 = 4096 + wid*512;

  int aoff[4][2], boff[2][2];
#pragma unroll
  for (int m=0;m<4;m++){
    int ia = wm*64 + m*16 + (lane & 15);
#pragma unroll
    for (int ks=0;ks<2;ks++)
      aoff[m][ks] = ia*128 + ((ks*64 + (lane>>4)*16) ^ ((ia & 7) << 4));
  }
#pragma unroll
  for (int n=0;n<2;n++){
    int ib = wn*32 + n*16 + (lane & 15);
#pragma unroll
    for (int ks=0;ks<2;ks++)
      boff[n][ks] = ib*128 + ((ks*64 + (lane>>4)*16) ^ ((ib & 7) << 4));
  }

  f32x4 acc[2][2][4][2];
#pragma unroll
  for (int qr=0;qr<2;qr++)
#pragma unroll
  for (int qc=0;qc<2;qc++)
#pragma unroll
  for (int m=0;m<4;m++)
#pragma unroll
  for (int n=0;n<2;n++) acc[qr][qc][m][n] = {0.f,0.f,0.f,0.f};

  bf16x8 a[4][2], bA[2][2], bB[2][2];

  KLOOP(NT);

  // plain-store epilogue: p[kh][ebase+row][col] = bf16 partial
  int r16 = ((lane >> 4) & 3)*4;
  unsigned short* pk = p + (size_t)kh*MAXROWS*H_DIM;
#pragma unroll
  for (int qr=0;qr<2;qr++){
#pragma unroll
    for (int m=0;m<4;m++){
#pragma unroll
      for (int j=0;j<4;j++){
        int gr = row0 + wm*128 + qr*64 + m*16 + r16 + j;
        if (gr < n_e){
          unsigned short* pr = pk + (size_t)(ebase + gr)*H_DIM;
#pragma unroll
          for (int qc=0;qc<2;qc++){
#pragma unroll
            for (int n=0;n<2;n++){
              int col = nt*256 + qc*128 + wn*32 + n*16 + (lane & 15);
              pr[col] = f2bf(acc[qr][qc][m][n][j]);
            }
          }
        }
      }
    }
  }
}

// ------- combine: out[t] = w0*sum_kh p[kh][s0] + w1*sum_kh p[kh][s1] --------
__global__ __launch_bounds__(256) void k_comb(const unsigned short* __restrict__ p,
                                              const int* __restrict__ slotof,
                                              const float* __restrict__ topv,
                                              float* __restrict__ out){
  int t = blockIdx.x;
  int c = threadIdx.x;                      // 4 cols each
  int col = c*4;
  int s0 = slotof[2*t], s1 = slotof[2*t+1];
  float w0 = topv[2*t], w1 = topv[2*t+1];
  float4 o = {0.f,0.f,0.f,0.f};
#pragma unroll
  for (int kh=0; kh<3; ++kh){
    const unsigned short* pk = p + (size_t)kh*MAXROWS*H_DIM;
    ushort4 a4 = *reinterpret_cast<const ushort4*>(pk + (size_t)s0*H_DIM + col);
    ushort4 b4 = *reinterpret_cast<const ushort4*>(pk + (size_t)s1*H_DIM + col);
    o.x += w0*bf2f(a4.x) + w1*bf2f(b4.x);
    o.y += w0*bf2f(a4.y) + w1*bf2f(b4.y);
    o.z += w0*bf2f(a4.z) + w1*bf2f(b4.z);
    o.w += w0*bf2f(a4.w) + w1*bf2f(b4.w);
  }
  reinterpret_cast<float4*>(out + (size_t)t*H_DIM)[c] = o;
}

// ---------------------------------------------------------------------------
extern "C" void kernel_launch(void* const* d_in, const int* in_sizes, int n_in,
                              void* d_out, int out_size, void* d_ws, size_t ws_size,
                              hipStream_t stream){
  const float* x  = (const float*)d_in[0];
  const float* rw = (const float*)d_in[1];
  const float* w1 = (const float*)d_in[2];
  const float* w2 = (const float*)d_in[3];
  const float* w3 = (const float*)d_in[4];
  float* out = (float*)d_out;

  char* ws = (char*)d_ws;
  size_t off = 0;
  unsigned short* xb  = (unsigned short*)(ws + off); off += (size_t)T_TOK*H_DIM*2;
  unsigned short* w1b = (unsigned short*)(ws + off); off += (size_t)E_NUM*F_DIM*H_DIM*2;
  unsigned short* w3b = (unsigned short*)(ws + off); off += (size_t)E_NUM*F_DIM*H_DIM*2;
  unsigned short* w2b = (unsigned short*)(ws + off); off += (size_t)E_NUM*H_DIM*F_DIM*2;
  unsigned short* hidden = (unsigned short*)(ws + off); off += (size_t)MAXROWS*F_DIM*2;
  int*   counts  = (int*)(ws + off); off += 64;   // [16] ints
  int*   cursors = (int*)(ws + off); off += 64;   // [16] ints
  int*   topi    = (int*)(ws + off); off += (size_t)T_TOK*2*4;
  float* topv    = (float*)(ws + off); off += (size_t)T_TOK*2*4;
  int*   entries = (int*)(ws + off); off += (size_t)MAXROWS*4;
  int*   slotof  = (int*)(ws + off); off += (size_t)T_TOK*2*4;
  // partials p[3][MAXROWS][H] bf16 aliased onto w1b+w3b (dead after k_ffn1):
  // 3*9984*1024*2 = 61.3 MB <= 64 MB
  unsigned short* p = w1b;

  hipFuncSetAttribute((const void*)k_ffn1,
                      hipFuncAttributeMaxDynamicSharedMemorySize, 131072);
  hipFuncSetAttribute((const void*)k_ffn2,
                      hipFuncAttributeMaxDynamicSharedMemorySize, 131072);

  hipMemsetAsync(counts, 0, 128, stream);   // counts[16] + cursors[16]

  k_pre<<<128 + 2*2048, 256, 0, stream>>>(x, rw, w1, w3, w1b, w3b, xb,
                                          counts, topi, topv);
  k_fill<<<T_TOK/256, 256, 0, stream>>>(topi, counts, cursors, entries, slotof);
  k_ffn1<<<624 + 384, 512, 131072, stream>>>(xb, w1b, w3b, counts, entries,
                                             hidden, w2, w2b);
  k_ffn2<<<MAXT256*12, 512, 131072, stream>>>(hidden, w2b, counts, p);
  k_comb<<<T_TOK, 256, 0, stream>>>(p, slotof, topv, out);
}